// Round 7
// baseline (124.948 us; speedup 1.0000x reference)
//
#include <hip/hip_runtime.h>
#include <hip/hip_bf16.h>
#include <stdint.h>

typedef __attribute__((ext_vector_type(4))) float f32x4;
typedef __attribute__((ext_vector_type(8))) short short8;

#define NN 4096      // nodes
#define FIN 128
#define FHID 64
#define BATCH 32
#define NJ 2048      // BATCH * FHID

// ---------- helpers ----------
__device__ __forceinline__ unsigned short f2bf(float f) {
  unsigned u = __builtin_bit_cast(unsigned, f);
  u = (u + 0x7FFFu + ((u >> 16) & 1u)) >> 16;   // RNE
  return (unsigned short)u;
}
__device__ __forceinline__ float bf2f(unsigned short h) {
  unsigned u = ((unsigned)h) << 16;
  return __builtin_bit_cast(float, u);
}
__device__ __forceinline__ void gload_lds16(const void* g, void* l) {
  __builtin_amdgcn_global_load_lds(
      (const __attribute__((address_space(1))) unsigned int*)g,
      (__attribute__((address_space(3))) unsigned int*)l, 16, 0, 0);
}

// ---------- K0: adj fp32 -> bf16 ----------
__global__ __launch_bounds__(256) void k_convert(const float* __restrict__ adj,
                                                 unsigned short* __restrict__ adjb) {
  long i = (long)blockIdx.x * 256 + threadIdx.x;
  const f32x4* in = (const f32x4*)adj;
  f32x4 v = in[i];
  ushort4 o;
  o.x = f2bf(v.x); o.y = f2bf(v.y); o.z = f2bf(v.z); o.w = f2bf(v.w);
  *(ushort4*)(adjb + i * 4) = o;
}

// ---------- K1: St[b*64+h][m] = sum_f x[b][m][f] * W1[f][h]  (bf16 out) ----------
__global__ __launch_bounds__(256) void k_support(const float* __restrict__ x,
                                                 const float* __restrict__ W1,
                                                 unsigned short* __restrict__ St) {
  __shared__ unsigned short W1t[FHID * 136];              // [h][f], pad 136
  __shared__ __align__(16) unsigned short T[FHID * 128];  // [h][m_loc]
  const int tid = threadIdx.x;
  for (int i = tid; i < FIN * FHID; i += 256) {
    int f = i >> 6, h = i & 63;
    W1t[h * 136 + f] = f2bf(W1[i]);
  }
  __syncthreads();

  const int bb = blockIdx.x >> 5;
  const int m0 = (blockIdx.x & 31) * 128;
  const int lane = tid & 63, wv = tid >> 6;
  const int fr = lane & 15, fq = lane >> 4;

  short8 bfr[4][4];
  #pragma unroll
  for (int ni = 0; ni < 4; ++ni)
    #pragma unroll
    for (int ks = 0; ks < 4; ++ks)
      bfr[ni][ks] = *(const short8*)&W1t[(ni * 16 + fr) * 136 + ks * 32 + fq * 8];

  const float* xr0 = x + ((size_t)bb * NN + m0 + wv * 32 + fr) * FIN;
  const float* xr1 = xr0 + (size_t)16 * FIN;

  f32x4 z = {0.f, 0.f, 0.f, 0.f};
  f32x4 acc[2][4];
  #pragma unroll
  for (int mf = 0; mf < 2; ++mf)
    #pragma unroll
    for (int ni = 0; ni < 4; ++ni) acc[mf][ni] = z;

  #pragma unroll
  for (int ks = 0; ks < 4; ++ks) {
    #pragma unroll
    for (int mf = 0; mf < 2; ++mf) {
      const float* src = (mf ? xr1 : xr0) + ks * 32 + fq * 8;
      f32x4 lo = *(const f32x4*)src;
      f32x4 hi = *(const f32x4*)(src + 4);
      short8 a;
      #pragma unroll
      for (int j = 0; j < 4; ++j) { a[j] = (short)f2bf(lo[j]); a[4 + j] = (short)f2bf(hi[j]); }
      #pragma unroll
      for (int ni = 0; ni < 4; ++ni)
        acc[mf][ni] = __builtin_amdgcn_mfma_f32_16x16x32_bf16(a, bfr[ni][ks], acc[mf][ni], 0, 0, 0);
    }
  }

  const int cr = (lane >> 4) * 4, cc = lane & 15;
  #pragma unroll
  for (int mf = 0; mf < 2; ++mf)
    #pragma unroll
    for (int ni = 0; ni < 4; ++ni) {
      ushort4 o;
      o.x = f2bf(acc[mf][ni][0]); o.y = f2bf(acc[mf][ni][1]);
      o.z = f2bf(acc[mf][ni][2]); o.w = f2bf(acc[mf][ni][3]);
      *(ushort4*)&T[(ni * 16 + cc) * 128 + wv * 32 + mf * 16 + cr] = o;
    }
  __syncthreads();
  for (int u = tid; u < FHID * 16; u += 256) {
    int row = u >> 4, ch = u & 15;
    *(short8*)(St + (size_t)(bb * FHID + row) * NN + m0 + ch * 8) =
        *(const short8*)&T[row * 128 + ch * 8];
  }
}

// ---------- K2: Hp[s] = adjb @ St^T  (K-split partial, bf16, no bias/relu) ----------
// BM=256 x BN=256, BK=64, Ksplit=2 (K=2048/block), 8 waves 2M x 4N,
// per-wave 128x64 (8x4 frags, 375 B LDS-read/MFMA). dbuf LDS 128 KB.
// 4 phases/K-tile, reads {12,4,8,0}, stages {0,2,2,4} into CUR buf (t+2),
// one vmcnt(4)/tile at P3 (derived: 12 outstanding, 4 newest = t+2 early).
// XOR-swizzle (byte ^= (row&7)<<4) via pre-swizzled global source.
#define VMW(N)  asm volatile("s_waitcnt vmcnt(" #N ")" ::: "memory")
#define LGKM0   asm volatile("s_waitcnt lgkmcnt(0)" ::: "memory")
#define BAR     __builtin_amdgcn_s_barrier()

__global__ __launch_bounds__(512, 2) void k_gemm(const unsigned short* __restrict__ A,
                                                 const unsigned short* __restrict__ Bt,
                                                 unsigned short* __restrict__ Hps) {
  __shared__ __align__(16) unsigned short As[2 * 16384];  // 256x64 dbuf, 64 KB
  __shared__ __align__(16) unsigned short Bs[2 * 16384];  // 256x64 dbuf, 64 KB

  const int tid  = threadIdx.x;
  const int lane = tid & 63;
  const int wv   = tid >> 6;
  const int wm   = wv >> 2;          // 0..1 (M half)
  const int wn   = wv & 3;           // 0..3 (N quarter)
  const int bm   = blockIdx.x * 256;
  const int bn   = blockIdx.y * 256;
  const int s    = blockIdx.z;       // K-split
  const int kb   = s * 2048;         // k base
  const int fr   = lane & 15;
  const int fq   = lane >> 4;

  // fragment LDS ushort offsets (buffer-relative)
  int offA[2][4][2], offB[2][2][2];
  #pragma unroll
  for (int mh = 0; mh < 2; ++mh)
    #pragma unroll
    for (int m2 = 0; m2 < 4; ++m2) {
      int row = wm * 128 + (mh * 4 + m2) * 16 + fr;
      #pragma unroll
      for (int ks = 0; ks < 2; ++ks)
        offA[mh][m2][ks] = row * 64 + ((((ks << 6) + (fq << 4)) ^ ((row & 7) << 4)) >> 1);
    }
  #pragma unroll
  for (int nh = 0; nh < 2; ++nh)
    #pragma unroll
    for (int n2 = 0; n2 < 2; ++n2) {
      int row = wn * 64 + (nh * 2 + n2) * 16 + fr;
      #pragma unroll
      for (int ks = 0; ks < 2; ++ks)
        offB[nh][n2][ks] = row * 64 + ((((ks << 6) + (fq << 4)) ^ ((row & 7) << 4)) >> 1);
    }

  // staging addresses (pre-swizzled global source, linear LDS dest)
  const int srow = tid >> 3;
  const int scol = ((((tid & 7) << 4) ^ ((srow & 7) << 4)) >> 1);
  const unsigned short* gA[4];
  const unsigned short* gB[4];
  #pragma unroll
  for (int c = 0; c < 4; ++c) {
    gA[c] = A  + (size_t)(bm + 64 * c + srow) * NN + kb + scol;
    gB[c] = Bt + (size_t)(bn + 64 * c + srow) * NN + kb + scol;
  }
  const int ld = tid * 8;

  f32x4 z = {0.f, 0.f, 0.f, 0.f};
  f32x4 acc[8][4];
  #pragma unroll
  for (int i = 0; i < 8; ++i)
    #pragma unroll
    for (int j = 0; j < 4; ++j) acc[i][j] = z;

  short8 av[4][2], bvA[2][2], bvB[2][2];

#define RD_AV(MH, Ac)                                                          \
    _Pragma("unroll") for (int m2 = 0; m2 < 4; ++m2)                           \
    _Pragma("unroll") for (int ks = 0; ks < 2; ++ks)                           \
      av[m2][ks] = *(const short8*)((Ac) + offA[MH][m2][ks]);
#define RD_BH(DST, Bb, NH)                                                     \
    _Pragma("unroll") for (int n2 = 0; n2 < 2; ++n2)                           \
    _Pragma("unroll") for (int ks = 0; ks < 2; ++ks)                           \
      DST[n2][ks] = *(const short8*)((Bb) + offB[NH][n2][ks]);
#define MFMA16(MH, BV, NH)                                                     \
    __builtin_amdgcn_s_setprio(1);                                             \
    _Pragma("unroll") for (int m2 = 0; m2 < 4; ++m2)                           \
    _Pragma("unroll") for (int n2 = 0; n2 < 2; ++n2)                           \
    _Pragma("unroll") for (int ks = 0; ks < 2; ++ks)                           \
      acc[4 * (MH) + m2][2 * (NH) + n2] = __builtin_amdgcn_mfma_f32_16x16x32_bf16( \
          av[m2][ks], BV[n2][ks], acc[4 * (MH) + m2][2 * (NH) + n2], 0, 0, 0); \
    __builtin_amdgcn_s_setprio(0);
#define SG_A(C, KO, BUF) gload_lds16(gA[C] + (KO), As + (BUF) * 16384 + (C) * 4096 + ld);
#define SG_B(C, KO, BUF) gload_lds16(gB[C] + (KO), Bs + (BUF) * 16384 + (C) * 4096 + ld);

// Guards: A0,A2 read P0 -> stage P1. B fully read after P1 -> B0,B1 stage P2.
// A1,A3 read P2 -> stage P3 (with B2,B3).
#define TILE(CUR, KQ, DOS, VMWOP) {                                            \
    const unsigned short* Ac = As + (CUR) * 16384;                             \
    const unsigned short* Bc = Bs + (CUR) * 16384;                             \
    /* P0 */                                                                   \
    RD_AV(0, Ac)                                                               \
    RD_BH(bvA, Bc, 0)                                                          \
    BAR; LGKM0;                                                                \
    MFMA16(0, bvA, 0)                                                          \
    /* P1 */                                                                   \
    RD_BH(bvB, Bc, 1)                                                          \
    if (DOS) { SG_A(0, KQ, CUR) SG_A(2, KQ, CUR) }                             \
    BAR; LGKM0;                                                                \
    MFMA16(0, bvB, 1)                                                          \
    /* P2 */                                                                   \
    RD_AV(1, Ac)                                                               \
    if (DOS) { SG_B(0, KQ, CUR) SG_B(1, KQ, CUR) }                             \
    BAR; LGKM0;                                                                \
    MFMA16(1, bvB, 1)                                                          \
    /* P3 */                                                                   \
    VMWOP;                                                                     \
    if (DOS) { SG_A(1, KQ, CUR) SG_A(3, KQ, CUR)                               \
               SG_B(2, KQ, CUR) SG_B(3, KQ, CUR) }                             \
    BAR;                                                                       \
    MFMA16(1, bvA, 0)                                                          \
  }

  // ---- prologue: tile0 -> buf0, tile1 -> buf1 (8 gloads each) ----
  #pragma unroll
  for (int c = 0; c < 4; ++c) { SG_A(c, 0, 0) SG_B(c, 0, 0) }
  #pragma unroll
  for (int c = 0; c < 4; ++c) { SG_A(c, 64, 1) SG_B(c, 64, 1) }
  VMW(8);                 // tile0 landed; tile1 in flight
  BAR;

  // ---- main loop: 15 iters = tiles 0..29 (stage t+2) ----
  int kq = 128;
  #pragma unroll 1
  for (int g = 0; g < 15; ++g) {
    TILE(0, kq,      1, VMW(4))
    TILE(1, kq + 64, 1, VMW(4))
    kq += 128;
  }
  // ---- tile 30 (buf0): no staging; drain for tile 31 ----
  TILE(0, 0, 0, VMW(0))
  // ---- tile 31 (buf1): last ----
  {
    const unsigned short* Ac = As + 16384;
    const unsigned short* Bc = Bs + 16384;
    RD_AV(0, Ac)
    RD_BH(bvA, Bc, 0)
    BAR; LGKM0;
    MFMA16(0, bvA, 0)
    RD_BH(bvB, Bc, 1)
    BAR; LGKM0;
    MFMA16(0, bvB, 1)
    RD_AV(1, Ac)
    BAR; LGKM0;
    MFMA16(1, bvB, 1)
    MFMA16(1, bvA, 0)
  }
#undef RD_AV
#undef RD_BH
#undef MFMA16
#undef SG_A
#undef SG_B
#undef TILE

  // ---- epilogue: store bf16 partial (bias/relu applied in k_agg) ----
  unsigned short* Hp = Hps + (size_t)s * NN * NJ;
  const int cr = (lane >> 4) * 4;
  const int cc = lane & 15;
  #pragma unroll
  for (int ni = 0; ni < 4; ++ni) {
    int col = bn + wn * 64 + ni * 16 + cc;
    #pragma unroll
    for (int mi = 0; mi < 8; ++mi) {
      int rowb = bm + wm * 128 + mi * 16 + cr;
      #pragma unroll
      for (int r = 0; r < 4; ++r)
        Hp[(size_t)(rowb + r) * NJ + col] = f2bf(acc[mi][ni][r]);
    }
  }
}

// ---------- K3: partial[b][c][h] = sum_n adj[q_b][n] * relu(Hp0+Hp1+b1) ----------
__global__ __launch_bounds__(256) void k_agg(const float* __restrict__ adj,
                                             const int* __restrict__ q_ids,
                                             const unsigned short* __restrict__ Hps,
                                             const float* __restrict__ b1,
                                             float* __restrict__ partial) {
  int b = blockIdx.x;        // 0..31
  int c = blockIdx.y;        // 0..15
  int h = threadIdx.x & 63;
  int w = threadIdx.x >> 6;
  int q = q_ids[b];
  const float* arow = adj + (long)q * NN;
  const unsigned short* H0 = Hps;
  const unsigned short* H1 = Hps + (size_t)NN * NJ;
  int j = b * FHID + h;
  float bias = b1[h];
  float sacc = 0.f;
  int n0 = c * 256;
  for (int n = n0 + w; n < n0 + 256; n += 4) {
    float hv = bf2f(H0[(size_t)n * NJ + j]) + bf2f(H1[(size_t)n * NJ + j]) + bias;
    sacc += arow[n] * (hv > 0.f ? hv : 0.f);
  }
  __shared__ float red[4][64];
  red[w][h] = sacc;
  __syncthreads();
  if (w == 0)
    partial[((b << 4) + c) * 64 + h] = red[0][h] + red[1][h] + red[2][h] + red[3][h];
}

// ---------- K4: out[b][l] = sum_h agg[b][h]*W2[h][l] + b2[l] ----------
__global__ __launch_bounds__(1024) void k_out(const float* __restrict__ partial,
                                              const float* __restrict__ W2,
                                              const float* __restrict__ b2,
                                              float* __restrict__ out) {
  __shared__ float aggs[BATCH * FHID];   // 2048
  int t = threadIdx.x;
  for (int idx = t; idx < BATCH * FHID; idx += 1024) {
    int base = (idx >> 6) * (16 * 64) + (idx & 63);
    float s = 0.f;
    #pragma unroll
    for (int c = 0; c < 16; ++c) s += partial[base + c * 64];
    aggs[idx] = s;
  }
  __syncthreads();
  int b = t >> 5, l = t & 31;
  float o = b2[l];
  #pragma unroll
  for (int h = 0; h < FHID; ++h) o += aggs[b * FHID + h] * W2[h * 32 + l];
  out[b * 32 + l] = o;
}

extern "C" void kernel_launch(void* const* d_in, const int* in_sizes, int n_in,
                              void* d_out, int out_size, void* d_ws, size_t ws_size,
                              hipStream_t stream) {
  const float* x   = (const float*)d_in[0];
  const int*   q   = (const int*)d_in[1];
  const float* adj = (const float*)d_in[2];
  const float* W1  = (const float*)d_in[3];
  const float* b1  = (const float*)d_in[4];
  const float* W2  = (const float*)d_in[5];
  const float* b2  = (const float*)d_in[6];
  float* out = (float*)d_out;

  char* ws = (char*)d_ws;
  unsigned short* adjb   = (unsigned short*)ws;                              // 32 MB
  unsigned short* St     = (unsigned short*)(ws + (size_t)32 * 1024 * 1024); // 16 MB
  unsigned short* Hps    = (unsigned short*)(ws + (size_t)48 * 1024 * 1024); // 32 MB (2 splits)
  float*          partial= (float*)(ws + (size_t)80 * 1024 * 1024);          // 128 KB

  // K0: adj -> bf16
  k_convert<<<(NN * NN / 4) / 256, 256, 0, stream>>>(adj, adjb);
  // K1: support^T via MFMA
  k_support<<<1024, 256, 0, stream>>>(x, W1, St);
  // K2: big GEMM partials (256x256 tiles, Ksplit=2, 4 phases/K-tile)
  dim3 g2(NN / 256, NJ / 256, 2);
  k_gemm<<<g2, 512, 0, stream>>>(adjb, St, Hps);
  // K3: row-gather aggregation + partial-sum + bias + relu
  dim3 g3(BATCH, 16);
  k_agg<<<g3, 256, 0, stream>>>(adj, q, Hps, b1, partial);
  // K4: final tiny GEMM
  k_out<<<1, 1024, 0, stream>>>(partial, W2, b2, out);
}